// Round 11
// baseline (2546.728 us; speedup 1.0000x reference)
//
#include <hip/hip_runtime.h>
#include <hip/hip_bf16.h>

typedef __attribute__((ext_vector_type(8))) __bf16 bf16x8;
typedef __attribute__((ext_vector_type(16))) float f32x16;
typedef __attribute__((ext_vector_type(4)))  float f32x4;

#define NB 256     // batch
#define HD 1024    // hidden
#define G3 3072    // 3*H
#define NT 128     // time steps

// ---------------- workspace layout (bytes) ----------------
static const size_t OFF_WHH  = 0;                                   // [d][3072][1024] bf16 (natural)
static const size_t OFF_WIH  = OFF_WHH + (size_t)2*G3*HD*2;         // [d][3072][1024] bf16 (natural)
static const size_t OFF_X16  = OFF_WIH + (size_t)2*G3*HD*2;         // [256][1024] bf16 (natural)
static const size_t OFF_CTR  = OFF_X16 + (size_t)NB*HD*2;           // 8 group counters, 128B apart (1KB)
static const size_t OFF_H16  = OFF_CTR + 1024;                      // [p][d][256][1024] bf16 (natural)
static const size_t OFF_PART = OFF_H16 + (size_t)4*NB*HD*2;         // [b][t][64] f32
// total ~36.2 MB

// ---------------- prep: cast to bf16, zero h16 parity 0, zero barrier ctrs ----------------
__global__ __launch_bounds__(256) void prep_kernel(
    const float* __restrict__ x,    const float* __restrict__ wihf,
    const float* __restrict__ whhf, const float* __restrict__ wihb,
    const float* __restrict__ whhb, char* __restrict__ ws)
{
  size_t i = (size_t)blockIdx.x*256 + threadIdx.x;   // grid covers 3145728
  __hip_bfloat16* whh = (__hip_bfloat16*)(ws+OFF_WHH);
  __hip_bfloat16* wih = (__hip_bfloat16*)(ws+OFF_WIH);
  __hip_bfloat16* x16 = (__hip_bfloat16*)(ws+OFF_X16);
  __hip_bfloat16* h16 = (__hip_bfloat16*)(ws+OFF_H16);
  if (blockIdx.x==0 && threadIdx.x<256) ((unsigned*)(ws+OFF_CTR))[threadIdx.x] = 0u;
  if (i < (size_t)G3*HD) {
    whh[i]                 = __float2bfloat16(whhf[i]);
    whh[(size_t)G3*HD + i] = __float2bfloat16(whhb[i]);
    wih[i]                 = __float2bfloat16(wihf[i]);
    wih[(size_t)G3*HD + i] = __float2bfloat16(wihb[i]);
  }
  if (i < (size_t)NB*HD)   x16[i] = __float2bfloat16(x[i]);
  if (i < (size_t)2*NB*HD) h16[i]  = __float2bfloat16(0.f);   // parity-0 plane, both dirs
}

// ---------------- coherent-bypass (sc0 sc1) helpers ----------------
__device__ inline f32x4 gload_cc(const void* p){
  f32x4 r;
  asm volatile("global_load_dwordx4 %0, %1, off sc0 sc1" : "=v"(r) : "v"(p) : "memory");
  return r;
}
__device__ inline void gstore_cc_d1(void* p, unsigned v){
  asm volatile("global_store_dword %0, %1, off sc0 sc1" :: "v"(p), "v"(v) : "memory");
}

// ---------------- persistent bidirectional GRU ----------------
// 256 blocks (1/CU, pinned by 104KB LDS), 512 threads = 8 waves = 8 K-slices of 128.
// __launch_bounds__(512,1): 1 block/CU -> 8 waves = 2 waves/SIMD -> 256-VGPR cap.
// (Round 10 used (512,2) which the toolchain treated as 2 blocks/CU -> 128-VGPR
// cap -> scratch spills -> 4 GB of FETCH. This round: single A buffer, ~225 regs.)
// Rows: two sequential 32-row halves (rh) sharing one A buffer and one acc.
// bid&7 = (d<<2)|rt sync group (32 jt-blocks per group, RMW counter barrier).
// W_hh frags resident in VGPR: B[3][8] = 96 VGPR for all 128 steps.
__global__ __launch_bounds__(512,1)
void gru_persist(char* __restrict__ ws,
                 const float* __restrict__ bihf, const float* __restrict__ bhhf,
                 const float* __restrict__ bihb, const float* __restrict__ bhhb,
                 const float* __restrict__ wout)
{
  const int bid = blockIdx.x;
  const int g8  = bid & 7;
  const int d   = g8 >> 2;
  const int rt  = g8 & 3;
  const int jt  = bid >> 3;
  const int tid = threadIdx.x;
  const int q   = tid >> 6;          // K-slice 0..7 (128 each)
  const int l   = tid & 63;
  const int lrow = l & 31;
  const int lh   = l >> 5;
  const int row_e = q*4 + (l>>4);    // epilogue row 0..31 within half
  const int ce    = (l & 15)*2;      // epilogue col pair 0..30
  const int r0 = rt*64, j0 = jt*32;

  const __hip_bfloat16* Wih = (const __hip_bfloat16*)(ws+OFF_WIH) + (size_t)d*G3*HD;
  const __hip_bfloat16* Whh = (const __hip_bfloat16*)(ws+OFF_WHH) + (size_t)d*G3*HD;
  const __hip_bfloat16* X16 = (const __hip_bfloat16*)(ws+OFF_X16);
  __hip_bfloat16* H16 = (__hip_bfloat16*)(ws+OFF_H16);
  unsigned* ctr = (unsigned*)(ws+OFF_CTR);
  float* part = (float*)(ws+OFF_PART);

  __shared__ float red[8][32][102];   // 104448 B; pad 102: conflict-free writes, <=4-way b64 reads

  const int kq = q*128 + lh*8;        // lane's base element offset in K

  bf16x8 B[3][8];                     // resident weight fragments (96 VGPR)
  #define LOADB(WSRC) { _Pragma("unroll") for (int g=0; g<3; ++g){ \
      const __hip_bfloat16* p0 = (WSRC) + (size_t)(g*1024 + j0 + lrow)*HD + kq; \
      _Pragma("unroll") for (int ks=0; ks<8; ++ks) B[g][ks] = *(const bf16x8*)(p0 + ks*16); } }

  f32x16 acc[3];
  #define ZACC { _Pragma("unroll") for (int g=0;g<3;++g) _Pragma("unroll") for (int e=0;e<16;++e) acc[g][e]=0.f; }
  #define MFMA8(AR) { _Pragma("unroll") for (int ks=0; ks<8; ++ks){ \
      bf16x8 a_ = __builtin_bit_cast(bf16x8, AR[ks]); \
      acc[0] = __builtin_amdgcn_mfma_f32_32x32x16_bf16(a_, B[0][ks], acc[0],0,0,0); \
      acc[1] = __builtin_amdgcn_mfma_f32_32x32x16_bf16(a_, B[1][ks], acc[1],0,0,0); \
      acc[2] = __builtin_amdgcn_mfma_f32_32x32x16_bf16(a_, B[2][ks], acc[2],0,0,0); } }
  #define WRED { _Pragma("unroll") for (int g=0;g<3;++g) _Pragma("unroll") for (int e=0;e<16;++e){ \
      int rl = (e&3) + 8*(e>>2) + 4*lh; red[q][rl][g*32 + lrow] = acc[g][e]; } }
  #define RRED(V) { _Pragma("unroll") for (int g=0;g<3;++g){ V[g][0]=0.f; V[g][1]=0.f; \
      _Pragma("unroll") for (int qq=0; qq<8; ++qq){ \
        float2 rd_ = *(const float2*)&red[qq][row_e][g*32 + ce]; V[g][0]+=rd_.x; V[g][1]+=rd_.y; } } }
  #define WAIT0 { asm volatile("s_waitcnt vmcnt(0)" ::: "memory"); __builtin_amdgcn_sched_barrier(0); }

  f32x4 A[8];                         // single staging buffer (32 VGPR), reused rh0->rh1
  #define ISSUE(PA) { _Pragma("unroll") for (int ks=0; ks<8; ++ks) A[ks] = gload_cc((PA) + ks*16); }

  // ---- INIT: gi = x @ W_ih^T, both row halves, captured to registers ----
  float gir[2][2], giz[2][2], gin[2][2], hst[2][2], v0[3][2], v1[3][2];
  LOADB(Wih);
  {
    const __hip_bfloat16* pa0 = X16 + (size_t)(r0 + lrow)*HD + kq;
    const __hip_bfloat16* pa1 = pa0 + 32*HD;
    ISSUE(pa0);
    WAIT0;
    ZACC; MFMA8(A);
    ISSUE(pa1);                     // WAR-safe: MFMAs issued, loads land during reduce
    WRED;
    __syncthreads();
    RRED(v0);
    __syncthreads();
    WAIT0;
    ZACC; MFMA8(A);
    WRED;
    __syncthreads();
    RRED(v1);
    __syncthreads();
  }
  const float* bih = d ? bihb : bihf;
  const float* bhh = d ? bhhb : bhhf;
  float bhn[2], wo2[2];
  #pragma unroll
  for (int c=0;c<2;++c){
    const int col = j0 + ce + c;
    gir[0][c] = v0[0][c] + bih[col]      + bhh[col];
    giz[0][c] = v0[1][c] + bih[1024+col] + bhh[1024+col];
    gin[0][c] = v0[2][c] + bih[2048+col];
    gir[1][c] = v1[0][c] + bih[col]      + bhh[col];
    giz[1][c] = v1[1][c] + bih[1024+col] + bhh[1024+col];
    gin[1][c] = v1[2][c] + bih[2048+col];
    bhn[c] = bhh[2048+col];
    wo2[c] = wout[d*HD + col];
    hst[0][c] = 0.f; hst[1][c] = 0.f;
  }

  LOADB(Whh);                          // recurrent weights resident from here on
  const size_t hplane = (size_t)2*NB*HD;

  #define EPILOGUE(RH, V, T, HD_PTR) { \
    float pp_ = 0.f; \
    _Pragma("unroll") for (int c=0;c<2;++c){ \
      float rr_ = 1.f/(1.f+__expf(-(gir[RH][c]+V[0][c]))); \
      float zz_ = 1.f/(1.f+__expf(-(giz[RH][c]+V[1][c]))); \
      float ng_ = tanhf(gin[RH][c] + rr_*(V[2][c]+bhn[c])); \
      hst[RH][c] = (1.f-zz_)*ng_ + zz_*hst[RH][c]; \
      pp_ += hst[RH][c]*wo2[c]; \
    } \
    const int grow_ = r0 + (RH)*32 + row_e; \
    unsigned u_ = (unsigned)__builtin_bit_cast(unsigned short, (__bf16)hst[RH][0]) \
                | ((unsigned)__builtin_bit_cast(unsigned short, (__bf16)hst[RH][1]) << 16); \
    gstore_cc_d1((HD_PTR) + (size_t)grow_*HD + j0 + ce, u_); \
    pp_ += __shfl_xor(pp_, 1, 64); pp_ += __shfl_xor(pp_, 2, 64); \
    pp_ += __shfl_xor(pp_, 4, 64); pp_ += __shfl_xor(pp_, 8, 64); \
    if ((l & 15) == 0) part[((size_t)grow_*NT + (T))*64 + d*32 + jt] = pp_; \
  }

  for (int t=0; t<NT; ++t){
    const __hip_bfloat16* hs = H16 + (size_t)(t&1)*hplane + (size_t)d*NB*HD;
    __hip_bfloat16*       hd = H16 + (size_t)((t+1)&1)*hplane + (size_t)d*NB*HD;
    const __hip_bfloat16* pa0 = hs + (size_t)(r0 + lrow)*HD + kq;
    const __hip_bfloat16* pa1 = pa0 + 32*HD;

    ISSUE(pa0);
    WAIT0;
    ZACC; MFMA8(A);
    ISSUE(pa1);                     // rh1 loads land during the rh0 reduce
    WRED;
    __syncthreads();
    RRED(v0);
    __syncthreads();                // red free for rh1
    WAIT0;                          // A ready (only the 8 rh1 loads outstanding)
    ZACC; MFMA8(A);
    EPILOGUE(0, v0, t, hd);         // rh0 gates+stores, overlaps rh1 red-write
    WRED;
    __syncthreads();
    RRED(v1);
    EPILOGUE(1, v1, t, hd);

    if (t < NT-1){
      asm volatile("s_waitcnt vmcnt(0)" ::: "memory");  // drain own h stores (per-wave)
      __syncthreads();
      if (tid == 0){
        atomicAdd(&ctr[g8*32], 1u);
        const unsigned tgt = 32u*(unsigned)(t+1);
        while (__hip_atomic_load(&ctr[g8*32], __ATOMIC_RELAXED, __HIP_MEMORY_SCOPE_AGENT) < tgt)
          __builtin_amdgcn_s_sleep(1);
      }
      __syncthreads();
    }
  }
}

// ---------------- finalize: one wave per (b,t) output, f32 OUTPUT ----------------
__global__ __launch_bounds__(256) void finalize_kernel(
    const char* __restrict__ ws, const float* __restrict__ bout,
    float* __restrict__ out)
{
  int widx = blockIdx.x*4 + (threadIdx.x>>6);   // output index b*128+t, 32768 total
  int lane = threadIdx.x & 63;
  const float* part = (const float*)(ws+OFF_PART);
  float v = part[(size_t)widx*64 + lane];
  #pragma unroll
  for (int m=1;m<64;m<<=1) v += __shfl_xor(v, m, 64);
  if (lane==0) out[widx] = v + bout[0];
}

// ---------------- launch ----------------
extern "C" void kernel_launch(void* const* d_in, const int* in_sizes, int n_in,
                              void* d_out, int out_size, void* d_ws, size_t ws_size,
                              hipStream_t stream)
{
  const float* x    = (const float*)d_in[0];
  // d_in[1] = n (always 128 for this problem)
  const float* wihf = (const float*)d_in[2];
  const float* whhf = (const float*)d_in[3];
  const float* bihf = (const float*)d_in[4];
  const float* bhhf = (const float*)d_in[5];
  const float* wihb = (const float*)d_in[6];
  const float* whhb = (const float*)d_in[7];
  const float* bihb = (const float*)d_in[8];
  const float* bhhb = (const float*)d_in[9];
  const float* wout = (const float*)d_in[10];
  const float* bout = (const float*)d_in[11];
  char* ws = (char*)d_ws;
  float* out = (float*)d_out;

  prep_kernel<<<12288, 256, 0, stream>>>(x, wihf, whhf, wihb, whhb, ws);
  gru_persist<<<256, 512, 0, stream>>>(ws, bihf, bhhf, bihb, bhhb, wout);
  finalize_kernel<<<8192, 256, 0, stream>>>(ws, bout, out);
}

// Round 12
// 2542.637 us; speedup vs baseline: 1.0016x; 1.0016x over previous
//
#include <hip/hip_runtime.h>
#include <hip/hip_bf16.h>

typedef __attribute__((ext_vector_type(8))) __bf16 bf16x8;
typedef __attribute__((ext_vector_type(16))) float f32x16;
typedef __attribute__((ext_vector_type(4)))  float f32x4;

#define NB 256     // batch
#define HD 1024    // hidden
#define G3 3072    // 3*H
#define NT 128     // time steps

// ---------------- workspace layout (bytes) ----------------
static const size_t OFF_WHH  = 0;                                   // [d][3072][1024] bf16 (natural)
static const size_t OFF_WIH  = OFF_WHH + (size_t)2*G3*HD*2;         // [d][3072][1024] bf16 (natural)
static const size_t OFF_X16  = OFF_WIH + (size_t)2*G3*HD*2;         // [256][1024] bf16 (natural)
static const size_t OFF_CTR  = OFF_X16 + (size_t)NB*HD*2;           // 8 group counters, 128B apart (1KB)
static const size_t OFF_H16  = OFF_CTR + 1024;                      // [p][d][256][1024] bf16 (natural)
static const size_t OFF_PART = OFF_H16 + (size_t)4*NB*HD*2;         // [b][t][64] f32
// total ~36.2 MB

// ---------------- prep: cast to bf16, zero h16 parity 0, zero barrier ctrs ----------------
__global__ __launch_bounds__(256) void prep_kernel(
    const float* __restrict__ x,    const float* __restrict__ wihf,
    const float* __restrict__ whhf, const float* __restrict__ wihb,
    const float* __restrict__ whhb, char* __restrict__ ws)
{
  size_t i = (size_t)blockIdx.x*256 + threadIdx.x;   // grid covers 3145728
  __hip_bfloat16* whh = (__hip_bfloat16*)(ws+OFF_WHH);
  __hip_bfloat16* wih = (__hip_bfloat16*)(ws+OFF_WIH);
  __hip_bfloat16* x16 = (__hip_bfloat16*)(ws+OFF_X16);
  __hip_bfloat16* h16 = (__hip_bfloat16*)(ws+OFF_H16);
  if (blockIdx.x==0 && threadIdx.x<256) ((unsigned*)(ws+OFF_CTR))[threadIdx.x] = 0u;
  if (i < (size_t)G3*HD) {
    whh[i]                 = __float2bfloat16(whhf[i]);
    whh[(size_t)G3*HD + i] = __float2bfloat16(whhb[i]);
    wih[i]                 = __float2bfloat16(wihf[i]);
    wih[(size_t)G3*HD + i] = __float2bfloat16(wihb[i]);
  }
  if (i < (size_t)NB*HD)   x16[i] = __float2bfloat16(x[i]);
  if (i < (size_t)2*NB*HD) h16[i]  = __float2bfloat16(0.f);   // parity-0 plane, both dirs
}

// ---------------- coherent-bypass (sc0 sc1) helpers ----------------
__device__ inline f32x4 gload_cc(const void* p){
  f32x4 r;
  asm volatile("global_load_dwordx4 %0, %1, off sc0 sc1" : "=v"(r) : "v"(p) : "memory");
  return r;
}
__device__ inline void gstore_cc_d1(void* p, unsigned v){
  asm volatile("global_store_dword %0, %1, off sc0 sc1" :: "v"(p), "v"(v) : "memory");
}

// ---------------- persistent bidirectional GRU ----------------
// 256 blocks (1/CU, pinned by 104KB LDS), 512 threads = 8 waves = 8 K-slices of 128.
// amdgpu_waves_per_eu(2,2): pins allocator target to 2 waves/EU (=1 block/CU for
// an 8-wave block) -> 256-VGPR budget. (Rounds 10/11: backend targeted 4 waves/EU
// -> 128 VGPRs -> ~220-reg demand spilled to scratch -> 3.95 GB FETCH, 2.6 ms.)
// Rows: two sequential 32-row halves (rh) sharing one A buffer and one acc.
// bid&7 = (d<<2)|rt sync group (32 jt-blocks per group, RMW counter barrier).
// W_hh frags resident in VGPR: B[3][8] = 96 VGPR for all 128 steps.
__global__ __attribute__((amdgpu_flat_work_group_size(512,512), amdgpu_waves_per_eu(2,2)))
void gru_persist(char* __restrict__ ws,
                 const float* __restrict__ bihf, const float* __restrict__ bhhf,
                 const float* __restrict__ bihb, const float* __restrict__ bhhb,
                 const float* __restrict__ wout)
{
  const int bid = blockIdx.x;
  const int g8  = bid & 7;
  const int d   = g8 >> 2;
  const int rt  = g8 & 3;
  const int jt  = bid >> 3;
  const int tid = threadIdx.x;
  const int q   = tid >> 6;          // K-slice 0..7 (128 each)
  const int l   = tid & 63;
  const int lrow = l & 31;
  const int lh   = l >> 5;
  const int row_e = q*4 + (l>>4);    // epilogue row 0..31 within half
  const int ce    = (l & 15)*2;      // epilogue col pair 0..30
  const int r0 = rt*64, j0 = jt*32;

  const __hip_bfloat16* Wih = (const __hip_bfloat16*)(ws+OFF_WIH) + (size_t)d*G3*HD;
  const __hip_bfloat16* Whh = (const __hip_bfloat16*)(ws+OFF_WHH) + (size_t)d*G3*HD;
  const __hip_bfloat16* X16 = (const __hip_bfloat16*)(ws+OFF_X16);
  __hip_bfloat16* H16 = (__hip_bfloat16*)(ws+OFF_H16);
  unsigned* ctr = (unsigned*)(ws+OFF_CTR);
  float* part = (float*)(ws+OFF_PART);

  __shared__ float red[8][32][102];   // 104448 B; pad 102: conflict-free writes, <=4-way b64 reads

  const int kq = q*128 + lh*8;        // lane's base element offset in K

  bf16x8 B[3][8];                     // resident weight fragments (96 VGPR)
  #define LOADB(WSRC) { _Pragma("unroll") for (int g=0; g<3; ++g){ \
      const __hip_bfloat16* p0 = (WSRC) + (size_t)(g*1024 + j0 + lrow)*HD + kq; \
      _Pragma("unroll") for (int ks=0; ks<8; ++ks) B[g][ks] = *(const bf16x8*)(p0 + ks*16); } }

  f32x16 acc[3];
  #define ZACC { _Pragma("unroll") for (int g=0;g<3;++g) _Pragma("unroll") for (int e=0;e<16;++e) acc[g][e]=0.f; }
  #define MFMA8(AR) { _Pragma("unroll") for (int ks=0; ks<8; ++ks){ \
      bf16x8 a_ = __builtin_bit_cast(bf16x8, AR[ks]); \
      acc[0] = __builtin_amdgcn_mfma_f32_32x32x16_bf16(a_, B[0][ks], acc[0],0,0,0); \
      acc[1] = __builtin_amdgcn_mfma_f32_32x32x16_bf16(a_, B[1][ks], acc[1],0,0,0); \
      acc[2] = __builtin_amdgcn_mfma_f32_32x32x16_bf16(a_, B[2][ks], acc[2],0,0,0); } }
  #define WRED { _Pragma("unroll") for (int g=0;g<3;++g) _Pragma("unroll") for (int e=0;e<16;++e){ \
      int rl = (e&3) + 8*(e>>2) + 4*lh; red[q][rl][g*32 + lrow] = acc[g][e]; } }
  #define RRED(V) { _Pragma("unroll") for (int g=0;g<3;++g){ V[g][0]=0.f; V[g][1]=0.f; \
      _Pragma("unroll") for (int qq=0; qq<8; ++qq){ \
        float2 rd_ = *(const float2*)&red[qq][row_e][g*32 + ce]; V[g][0]+=rd_.x; V[g][1]+=rd_.y; } } }
  #define WAIT0 { asm volatile("s_waitcnt vmcnt(0)" ::: "memory"); __builtin_amdgcn_sched_barrier(0); }

  f32x4 A[8];                         // single staging buffer (32 VGPR), reused rh0->rh1
  #define ISSUE(PA) { _Pragma("unroll") for (int ks=0; ks<8; ++ks) A[ks] = gload_cc((PA) + ks*16); }

  // ---- INIT: gi = x @ W_ih^T, both row halves, captured to registers ----
  float gir[2][2], giz[2][2], gin[2][2], hst[2][2], v0[3][2], v1[3][2];
  LOADB(Wih);
  {
    const __hip_bfloat16* pa0 = X16 + (size_t)(r0 + lrow)*HD + kq;
    const __hip_bfloat16* pa1 = pa0 + 32*HD;
    ISSUE(pa0);
    WAIT0;
    ZACC; MFMA8(A);
    ISSUE(pa1);                     // WAR-safe: MFMAs issued, loads land during reduce
    WRED;
    __syncthreads();
    RRED(v0);
    __syncthreads();
    WAIT0;
    ZACC; MFMA8(A);
    WRED;
    __syncthreads();
    RRED(v1);
    __syncthreads();
  }
  const float* bih = d ? bihb : bihf;
  const float* bhh = d ? bhhb : bhhf;
  float bhn[2], wo2[2];
  #pragma unroll
  for (int c=0;c<2;++c){
    const int col = j0 + ce + c;
    gir[0][c] = v0[0][c] + bih[col]      + bhh[col];
    giz[0][c] = v0[1][c] + bih[1024+col] + bhh[1024+col];
    gin[0][c] = v0[2][c] + bih[2048+col];
    gir[1][c] = v1[0][c] + bih[col]      + bhh[col];
    giz[1][c] = v1[1][c] + bih[1024+col] + bhh[1024+col];
    gin[1][c] = v1[2][c] + bih[2048+col];
    bhn[c] = bhh[2048+col];
    wo2[c] = wout[d*HD + col];
    hst[0][c] = 0.f; hst[1][c] = 0.f;
  }

  LOADB(Whh);                          // recurrent weights resident from here on
  const size_t hplane = (size_t)2*NB*HD;

  #define EPILOGUE(RH, V, T, HD_PTR) { \
    float pp_ = 0.f; \
    _Pragma("unroll") for (int c=0;c<2;++c){ \
      float rr_ = 1.f/(1.f+__expf(-(gir[RH][c]+V[0][c]))); \
      float zz_ = 1.f/(1.f+__expf(-(giz[RH][c]+V[1][c]))); \
      float ng_ = tanhf(gin[RH][c] + rr_*(V[2][c]+bhn[c])); \
      hst[RH][c] = (1.f-zz_)*ng_ + zz_*hst[RH][c]; \
      pp_ += hst[RH][c]*wo2[c]; \
    } \
    const int grow_ = r0 + (RH)*32 + row_e; \
    unsigned u_ = (unsigned)__builtin_bit_cast(unsigned short, (__bf16)hst[RH][0]) \
                | ((unsigned)__builtin_bit_cast(unsigned short, (__bf16)hst[RH][1]) << 16); \
    gstore_cc_d1((HD_PTR) + (size_t)grow_*HD + j0 + ce, u_); \
    pp_ += __shfl_xor(pp_, 1, 64); pp_ += __shfl_xor(pp_, 2, 64); \
    pp_ += __shfl_xor(pp_, 4, 64); pp_ += __shfl_xor(pp_, 8, 64); \
    if ((l & 15) == 0) part[((size_t)grow_*NT + (T))*64 + d*32 + jt] = pp_; \
  }

  for (int t=0; t<NT; ++t){
    const __hip_bfloat16* hs = H16 + (size_t)(t&1)*hplane + (size_t)d*NB*HD;
    __hip_bfloat16*       hd = H16 + (size_t)((t+1)&1)*hplane + (size_t)d*NB*HD;
    const __hip_bfloat16* pa0 = hs + (size_t)(r0 + lrow)*HD + kq;
    const __hip_bfloat16* pa1 = pa0 + 32*HD;

    ISSUE(pa0);
    WAIT0;
    ZACC; MFMA8(A);
    ISSUE(pa1);                     // rh1 loads land during the rh0 reduce
    WRED;
    __syncthreads();
    RRED(v0);
    __syncthreads();                // red free for rh1
    WAIT0;                          // A ready (only the 8 rh1 loads outstanding)
    ZACC; MFMA8(A);
    EPILOGUE(0, v0, t, hd);         // rh0 gates+stores, overlaps rh1 red-write
    WRED;
    __syncthreads();
    RRED(v1);
    EPILOGUE(1, v1, t, hd);

    if (t < NT-1){
      asm volatile("s_waitcnt vmcnt(0)" ::: "memory");  // drain own h stores (per-wave)
      __syncthreads();
      if (tid == 0){
        atomicAdd(&ctr[g8*32], 1u);
        const unsigned tgt = 32u*(unsigned)(t+1);
        while (__hip_atomic_load(&ctr[g8*32], __ATOMIC_RELAXED, __HIP_MEMORY_SCOPE_AGENT) < tgt)
          __builtin_amdgcn_s_sleep(1);
      }
      __syncthreads();
    }
  }
}

// ---------------- finalize: one wave per (b,t) output, f32 OUTPUT ----------------
__global__ __launch_bounds__(256) void finalize_kernel(
    const char* __restrict__ ws, const float* __restrict__ bout,
    float* __restrict__ out)
{
  int widx = blockIdx.x*4 + (threadIdx.x>>6);   // output index b*128+t, 32768 total
  int lane = threadIdx.x & 63;
  const float* part = (const float*)(ws+OFF_PART);
  float v = part[(size_t)widx*64 + lane];
  #pragma unroll
  for (int m=1;m<64;m<<=1) v += __shfl_xor(v, m, 64);
  if (lane==0) out[widx] = v + bout[0];
}

// ---------------- launch ----------------
extern "C" void kernel_launch(void* const* d_in, const int* in_sizes, int n_in,
                              void* d_out, int out_size, void* d_ws, size_t ws_size,
                              hipStream_t stream)
{
  const float* x    = (const float*)d_in[0];
  // d_in[1] = n (always 128 for this problem)
  const float* wihf = (const float*)d_in[2];
  const float* whhf = (const float*)d_in[3];
  const float* bihf = (const float*)d_in[4];
  const float* bhhf = (const float*)d_in[5];
  const float* wihb = (const float*)d_in[6];
  const float* whhb = (const float*)d_in[7];
  const float* bihb = (const float*)d_in[8];
  const float* bhhb = (const float*)d_in[9];
  const float* wout = (const float*)d_in[10];
  const float* bout = (const float*)d_in[11];
  char* ws = (char*)d_ws;
  float* out = (float*)d_out;

  prep_kernel<<<12288, 256, 0, stream>>>(x, wihf, whhf, wihb, whhb, ws);
  gru_persist<<<256, 512, 0, stream>>>(ws, bihf, bhhf, bihb, bhhb, wout);
  finalize_kernel<<<8192, 256, 0, stream>>>(ws, bout, out);
}

// Round 13
// 1649.163 us; speedup vs baseline: 1.5443x; 1.5418x over previous
//
#include <hip/hip_runtime.h>
#include <hip/hip_bf16.h>

typedef __attribute__((ext_vector_type(8))) __bf16 bf16x8;
typedef __attribute__((ext_vector_type(16))) float f32x16;
typedef __attribute__((ext_vector_type(4)))  float f32x4;
typedef __attribute__((ext_vector_type(2)))  unsigned u32x2;

#define NB 256     // batch
#define HD 1024    // hidden
#define G3 3072    // 3*H
#define NT 128     // time steps

// ---------------- workspace layout (bytes) ----------------
static const size_t OFF_WHH  = 0;                                   // [d][3072][1024] bf16
static const size_t OFF_WIH  = OFF_WHH + (size_t)2*G3*HD*2;         // [d][3072][1024] bf16
static const size_t OFF_X16  = OFF_WIH + (size_t)2*G3*HD*2;         // [256][1024] bf16
static const size_t OFF_FLG  = OFF_X16 + (size_t)NB*HD*2;           // 16 groups x 32 producers, 128B stride = 64KB
static const size_t OFF_H16  = OFF_FLG + 65536;                     // [p][d][256][1024] bf16
static const size_t OFF_PART = OFF_H16 + (size_t)4*NB*HD*2;         // [b][t][64] f32
// total ~36.2 MB

// ---------------- prep: cast to bf16, zero h16 plane 0, zero flags ----------------
__global__ __launch_bounds__(256) void prep_kernel(
    const float* __restrict__ x,    const float* __restrict__ wihf,
    const float* __restrict__ whhf, const float* __restrict__ wihb,
    const float* __restrict__ whhb, char* __restrict__ ws)
{
  size_t i = (size_t)blockIdx.x*256 + threadIdx.x;   // grid covers 3145728
  __hip_bfloat16* whh = (__hip_bfloat16*)(ws+OFF_WHH);
  __hip_bfloat16* wih = (__hip_bfloat16*)(ws+OFF_WIH);
  __hip_bfloat16* x16 = (__hip_bfloat16*)(ws+OFF_X16);
  __hip_bfloat16* h16 = (__hip_bfloat16*)(ws+OFF_H16);
  if (i < 16384) ((unsigned*)(ws+OFF_FLG))[i] = 0u;
  if (i < (size_t)G3*HD) {
    whh[i]                 = __float2bfloat16(whhf[i]);
    whh[(size_t)G3*HD + i] = __float2bfloat16(whhb[i]);
    wih[i]                 = __float2bfloat16(wihf[i]);
    wih[(size_t)G3*HD + i] = __float2bfloat16(wihb[i]);
  }
  if (i < (size_t)NB*HD)   x16[i] = __float2bfloat16(x[i]);
  if (i < (size_t)2*NB*HD) h16[i]  = __float2bfloat16(0.f);   // plane 0, both dirs
}

// ---------------- asm load/store helpers ----------------
__device__ inline f32x4 gload_cc(const void* p){         // coherent bypass (h via L3)
  f32x4 r;
  asm volatile("global_load_dwordx4 %0, %1, off sc0 sc1" : "=v"(r) : "v"(p) : "memory");
  return r;
}
__device__ inline f32x4 gload_nc(const void* p){         // cached (weights), vmcnt-counted
  f32x4 r;
  asm volatile("global_load_dwordx4 %0, %1, off" : "=v"(r) : "v"(p) : "memory");
  return r;
}
__device__ inline void gstore_cc_d2(void* p, u32x2 v){
  asm volatile("global_store_dwordx2 %0, %1, off sc0 sc1" :: "v"(p), "v"(v) : "memory");
}
#define WAITV0 { asm volatile("s_waitcnt vmcnt(0)" ::: "memory"); __builtin_amdgcn_sched_barrier(0); }

// ---------------- persistent bidirectional GRU ----------------
// 512 blocks (2/CU: LDS 77824B, VGPR capped 256 by __launch_bounds__(256,2)),
// 256 threads = 4 waves (K-slices of 256). Block = 32 rows x 32 cols.
// bid: gg = bid&15 = (d<<3)|rt (sync group of 32 col-tile blocks), jt = bid>>4.
// Br/Bz (gates r,z) resident in VGPR (128); gate-n weights streamed per step via
// cached loads (any 64 blocks/XCD hold exactly 4MB of gate-n rows = L2-sized;
// read-only, so XCD placement affects speed only). h exchange: sc0sc1 (L3).
// Sync: per-producer flags -- wave q needs h cols [256q,256q+256) = producers
// jp=8q..8q+7 only; spins on those 8 flags (lanes 0..7), so loads start as soon
// as the needed producers finish. Union over waves = whole group => 2-plane WAR
// safety proof as before (epilogue runs after block-wide sync joins all waves).
__global__ __launch_bounds__(256,2)
void gru_persist(char* __restrict__ ws,
                 const float* __restrict__ bihf, const float* __restrict__ bhhf,
                 const float* __restrict__ bihb, const float* __restrict__ bhhb,
                 const float* __restrict__ wout)
{
  const int bid = blockIdx.x;
  const int gg  = bid & 15;          // sync group (d, rt)
  const int d   = gg >> 3;
  const int rt  = gg & 7;
  const int jt  = bid >> 4;          // 0..31
  const int tid = threadIdx.x;
  const int q   = tid >> 6;          // wave / K-slice (256 each)
  const int l   = tid & 63;
  const int lrow = l & 31;
  const int lh   = l >> 5;
  const int row_e = tid >> 3;        // epilogue row 0..31
  const int c0    = (tid & 7) * 4;   // epilogue col quad 0..28
  const int r0 = rt*32, j0 = jt*32;

  const __hip_bfloat16* Wih = (const __hip_bfloat16*)(ws+OFF_WIH) + (size_t)d*G3*HD;
  const __hip_bfloat16* Whh = (const __hip_bfloat16*)(ws+OFF_WHH) + (size_t)d*G3*HD;
  const __hip_bfloat16* X16 = (const __hip_bfloat16*)(ws+OFF_X16);
  __hip_bfloat16* H16 = (__hip_bfloat16*)(ws+OFF_H16);        // [p][d][NB][HD]
  unsigned* flg = (unsigned*)(ws+OFF_FLG);
  float* part = (float*)(ws+OFF_PART);

  __shared__ float red[4][32][104];   // 53248B: K-slice partials (r|z|n at col offs 0/32/64)
  __shared__ float aux[256][24];      // 24576B: [0:12) gi_rzn, [12:16) hst, [16:20) bhn, [20:24) wo

  const int kq = q*256 + lh*8;        // lane's base element offset in K

  bf16x8 Br[16], Bz[16];              // resident r,z weight fragments (128 VGPR)
  #define LOADRZ(W) { _Pragma("unroll") for (int ks=0;ks<16;++ks){ \
      Br[ks] = *(const bf16x8*)((W) + (size_t)(       j0 + lrow)*HD + kq + ks*16); \
      Bz[ks] = *(const bf16x8*)((W) + (size_t)(1024 + j0 + lrow)*HD + kq + ks*16); } }

  f32x16 acc0, acc1, acc2;
  f32x4 A4[4], Bn4[4];

  // gemm: 4 quarters; per quarter issue 4 Bn (cached) + 4 A (sc) loads, drain, 12 MFMA.
  auto gemm = [&](const __hip_bfloat16* pa, const __hip_bfloat16* pn){
    #pragma unroll
    for (int e=0;e<16;++e){ acc0[e]=0.f; acc1[e]=0.f; acc2[e]=0.f; }
    #pragma unroll
    for (int bt=0; bt<4; ++bt){
      #pragma unroll
      for (int ks=0;ks<4;++ks) Bn4[ks] = gload_nc(pn + (bt*4+ks)*16);
      #pragma unroll
      for (int ks=0;ks<4;++ks) A4[ks]  = gload_cc(pa + (bt*4+ks)*16);
      WAITV0;
      #pragma unroll
      for (int ks=0;ks<4;++ks){
        bf16x8 a  = __builtin_bit_cast(bf16x8, A4[ks]);
        bf16x8 bn = __builtin_bit_cast(bf16x8, Bn4[ks]);
        acc0 = __builtin_amdgcn_mfma_f32_32x32x16_bf16(a, Br[bt*4+ks], acc0,0,0,0);
        acc1 = __builtin_amdgcn_mfma_f32_32x32x16_bf16(a, Bz[bt*4+ks], acc1,0,0,0);
        acc2 = __builtin_amdgcn_mfma_f32_32x32x16_bf16(a, bn,          acc2,0,0,0);
      }
    }
  };

  #define WRED { _Pragma("unroll") for (int e=0;e<16;++e){ \
      int rl=(e&3)+8*(e>>2)+4*lh; \
      red[q][rl][     lrow]=acc0[e]; \
      red[q][rl][32 + lrow]=acc1[e]; \
      red[q][rl][64 + lrow]=acc2[e]; } }

  float v0[4], v1[4], v2[4];
  #define RRED { float4 s0={0,0,0,0}, s1={0,0,0,0}, s2={0,0,0,0}; \
    _Pragma("unroll") for (int qq=0;qq<4;++qq){ \
      float4 a_=*(const float4*)&red[qq][row_e][c0]; \
      float4 b_=*(const float4*)&red[qq][row_e][32+c0]; \
      float4 g_=*(const float4*)&red[qq][row_e][64+c0]; \
      s0.x+=a_.x; s0.y+=a_.y; s0.z+=a_.z; s0.w+=a_.w; \
      s1.x+=b_.x; s1.y+=b_.y; s1.z+=b_.z; s1.w+=b_.w; \
      s2.x+=g_.x; s2.y+=g_.y; s2.z+=g_.z; s2.w+=g_.w; } \
    v0[0]=s0.x; v0[1]=s0.y; v0[2]=s0.z; v0[3]=s0.w; \
    v1[0]=s1.x; v1[1]=s1.y; v1[2]=s1.z; v1[3]=s1.w; \
    v2[0]=s2.x; v2[1]=s2.y; v2[2]=s2.z; v2[3]=s2.w; }

  const __hip_bfloat16* pnW = Whh + (size_t)(2048 + j0 + lrow)*HD + kq;  // streamed gate-n rows

  // ---- INIT: gi = x @ W_ih^T (+ biases), stored to aux; hst=0 ----
  LOADRZ(Wih);
  gemm(X16 + (size_t)(r0 + lrow)*HD + kq, Wih + (size_t)(2048 + j0 + lrow)*HD + kq);
  WRED; __syncthreads(); RRED; __syncthreads();
  {
    const float* bih = d ? bihb : bihf;
    const float* bhh = d ? bhhb : bhhf;
    #pragma unroll
    for (int c=0;c<4;++c){
      const int col = j0 + c0 + c;
      aux[tid][0 +c] = v0[c] + bih[col]      + bhh[col];
      aux[tid][4 +c] = v1[c] + bih[1024+col] + bhh[1024+col];
      aux[tid][8 +c] = v2[c] + bih[2048+col];
      aux[tid][12+c] = 0.f;
      aux[tid][16+c] = bhh[2048+col];
      aux[tid][20+c] = wout[d*HD + col];
    }
  }
  LOADRZ(Whh);                        // resident recurrent r,z weights from here on

  const size_t hplane = (size_t)2*NB*HD;
  const __hip_bfloat16* paBase = H16 + (size_t)d*NB*HD + (size_t)(r0 + lrow)*HD + kq;
  const int grow = r0 + row_e;

  for (int t=0; t<NT; ++t){
    // wave-level spin on this wave's 8 producer flags (trivially passes at t=0)
    if (t){
      const unsigned tgt = (unsigned)t;
      unsigned* fp = flg + (size_t)(gg*32 + q*8 + (l & 7))*32;
      for(;;){
        unsigned v = (l < 8) ? __hip_atomic_load(fp, __ATOMIC_RELAXED, __HIP_MEMORY_SCOPE_AGENT) : tgt;
        if (__all((int)(v >= tgt))) break;
        __builtin_amdgcn_s_sleep(1);
      }
    }

    gemm(paBase + (size_t)(t&1)*hplane, pnW);
    WRED; __syncthreads(); RRED; __syncthreads();

    // epilogue: gates for 4 cols of one row; h-store (sc, 8B); out-partial
    {
      float pp = 0.f;
      unsigned hw[2];
      #pragma unroll
      for (int c2=0;c2<2;++c2){
        unsigned u = 0;
        #pragma unroll
        for (int c1=0;c1<2;++c1){
          const int c = c2*2 + c1;
          float rr = 1.f/(1.f+__expf(-(aux[tid][0+c] + v0[c])));
          float zz = 1.f/(1.f+__expf(-(aux[tid][4+c] + v1[c])));
          float ng = tanhf(aux[tid][8+c] + rr*(v2[c] + aux[tid][16+c]));
          float hn = (1.f-zz)*ng + zz*aux[tid][12+c];
          aux[tid][12+c] = hn;
          pp += hn * aux[tid][20+c];
          u |= ((unsigned)__builtin_bit_cast(unsigned short, (__bf16)hn)) << (16*c1);
        }
        hw[c2] = u;
      }
      __hip_bfloat16* hd = H16 + (size_t)((t+1)&1)*hplane + (size_t)d*NB*HD;
      u32x2 hv; hv[0]=hw[0]; hv[1]=hw[1];
      gstore_cc_d2(hd + (size_t)grow*HD + j0 + c0, hv);
      pp += __shfl_xor(pp, 1, 64);
      pp += __shfl_xor(pp, 2, 64);
      pp += __shfl_xor(pp, 4, 64);
      if ((l & 7) == 0) part[((size_t)grow*NT + t)*64 + d*32 + jt] = pp;
    }

    // release: per-wave drain, block-wide join, one flag bump per block
    WAITV0;
    __syncthreads();
    if (t+1 < NT && tid == 0) atomicAdd(flg + (size_t)(gg*32 + jt)*32, 1u);
  }
}

// ---------------- finalize: one wave per (b,t) output, f32 OUTPUT ----------------
__global__ __launch_bounds__(256) void finalize_kernel(
    const char* __restrict__ ws, const float* __restrict__ bout,
    float* __restrict__ out)
{
  int widx = blockIdx.x*4 + (threadIdx.x>>6);   // output index b*128+t, 32768 total
  int lane = threadIdx.x & 63;
  const float* part = (const float*)(ws+OFF_PART);
  float v = part[(size_t)widx*64 + lane];
  #pragma unroll
  for (int m=1;m<64;m<<=1) v += __shfl_xor(v, m, 64);
  if (lane==0) out[widx] = v + bout[0];
}

// ---------------- launch ----------------
extern "C" void kernel_launch(void* const* d_in, const int* in_sizes, int n_in,
                              void* d_out, int out_size, void* d_ws, size_t ws_size,
                              hipStream_t stream)
{
  const float* x    = (const float*)d_in[0];
  // d_in[1] = n (always 128 for this problem)
  const float* wihf = (const float*)d_in[2];
  const float* whhf = (const float*)d_in[3];
  const float* bihf = (const float*)d_in[4];
  const float* bhhf = (const float*)d_in[5];
  const float* wihb = (const float*)d_in[6];
  const float* whhb = (const float*)d_in[7];
  const float* bihb = (const float*)d_in[8];
  const float* bhhb = (const float*)d_in[9];
  const float* wout = (const float*)d_in[10];
  const float* bout = (const float*)d_in[11];
  char* ws = (char*)d_ws;
  float* out = (float*)d_out;

  prep_kernel<<<12288, 256, 0, stream>>>(x, wihf, whhf, wihb, whhb, ws);
  gru_persist<<<512, 256, 0, stream>>>(ws, bihf, bhhf, bihb, bhhb, wout);
  finalize_kernel<<<8192, 256, 0, stream>>>(ws, bout, out);
}

// Round 14
// 1467.194 us; speedup vs baseline: 1.7358x; 1.1240x over previous
//
#include <hip/hip_runtime.h>
#include <hip/hip_bf16.h>

typedef __attribute__((ext_vector_type(8))) __bf16 bf16x8;
typedef __attribute__((ext_vector_type(16))) float f32x16;
typedef __attribute__((ext_vector_type(4)))  float f32x4;
typedef __attribute__((ext_vector_type(2)))  unsigned u32x2;

#define NB 256     // batch
#define HD 1024    // hidden
#define G3 3072    // 3*H
#define NT 128     // time steps

// ---------------- workspace layout (bytes) ----------------
static const size_t OFF_WHH  = 0;                                   // [d][3072][1024] bf16
static const size_t OFF_WIH  = OFF_WHH + (size_t)2*G3*HD*2;         // [d][3072][1024] bf16
static const size_t OFF_X16  = OFF_WIH + (size_t)2*G3*HD*2;         // [256][1024] bf16
static const size_t OFF_FLG  = OFF_X16 + (size_t)NB*HD*2;           // 16 groups x 32 producers, 128B stride = 64KB
static const size_t OFF_H16  = OFF_FLG + 65536;                     // [p][d][256][1024] bf16
static const size_t OFF_PART = OFF_H16 + (size_t)4*NB*HD*2;         // [b][t][64] f32
// total ~36.2 MB

// ---------------- prep: cast to bf16, zero h16 plane 0, zero flags ----------------
__global__ __launch_bounds__(256) void prep_kernel(
    const float* __restrict__ x,    const float* __restrict__ wihf,
    const float* __restrict__ whhf, const float* __restrict__ wihb,
    const float* __restrict__ whhb, char* __restrict__ ws)
{
  size_t i = (size_t)blockIdx.x*256 + threadIdx.x;   // grid covers 3145728
  __hip_bfloat16* whh = (__hip_bfloat16*)(ws+OFF_WHH);
  __hip_bfloat16* wih = (__hip_bfloat16*)(ws+OFF_WIH);
  __hip_bfloat16* x16 = (__hip_bfloat16*)(ws+OFF_X16);
  __hip_bfloat16* h16 = (__hip_bfloat16*)(ws+OFF_H16);
  if (i < 16384) ((unsigned*)(ws+OFF_FLG))[i] = 0u;
  if (i < (size_t)G3*HD) {
    whh[i]                 = __float2bfloat16(whhf[i]);
    whh[(size_t)G3*HD + i] = __float2bfloat16(whhb[i]);
    wih[i]                 = __float2bfloat16(wihf[i]);
    wih[(size_t)G3*HD + i] = __float2bfloat16(wihb[i]);
  }
  if (i < (size_t)NB*HD)   x16[i] = __float2bfloat16(x[i]);
  if (i < (size_t)2*NB*HD) h16[i]  = __float2bfloat16(0.f);   // plane 0, both dirs
}

// ---------------- asm load/store helpers ----------------
__device__ inline f32x4 gload_cc(const void* p){         // coherent bypass (h via L3)
  f32x4 r;
  asm volatile("global_load_dwordx4 %0, %1, off sc0 sc1" : "=v"(r) : "v"(p) : "memory");
  return r;
}
__device__ inline f32x4 gload_nc(const void* p){         // cached (weights)
  f32x4 r;
  asm volatile("global_load_dwordx4 %0, %1, off" : "=v"(r) : "v"(p) : "memory");
  return r;
}
__device__ inline void gstore_cc_d2(void* p, u32x2 v){
  asm volatile("global_store_dwordx2 %0, %1, off sc0 sc1" :: "v"(p), "v"(v) : "memory");
}
#define WAITV0 { asm volatile("s_waitcnt vmcnt(0)" ::: "memory"); __builtin_amdgcn_sched_barrier(0); }

// ---------------- persistent bidirectional GRU ----------------
// 512 blocks (2/CU), 256 threads = 4 waves (K-slices of 256). Block = 32r x 32c.
// gg = bid&15 = (rt<<1)|d. XCD = bid%8 = gg%8 -> XCD c hosts groups {c, c+8},
// which share d = c&1: per-XCD streamed gate-n working set = 2 MB (one
// direction) -> L2-resident. (Round 13: d=gg>>3 put BOTH directions on each
// XCD = 4 MB = whole L2 -> thrash -> 19 MB/step HBM = the entire step time.)
// Br/Bz resident in regs; gate-n streamed cached; h exchange sc0sc1 (L3).
// Sync: per-producer flags (wave q spins on its 8 producers only).
__global__ __launch_bounds__(256,2)
void gru_persist(char* __restrict__ ws,
                 const float* __restrict__ bihf, const float* __restrict__ bhhf,
                 const float* __restrict__ bihb, const float* __restrict__ bhhb,
                 const float* __restrict__ wout)
{
  const int bid = blockIdx.x;
  const int gg  = bid & 15;          // sync group
  const int d   = gg & 1;            // direction (LOW bit: keeps one dir per XCD)
  const int rt  = gg >> 1;           // row tile 0..7 (32 rows)
  const int jt  = bid >> 4;          // 0..31
  const int tid = threadIdx.x;
  const int q   = tid >> 6;          // wave / K-slice (256 each)
  const int l   = tid & 63;
  const int lrow = l & 31;
  const int lh   = l >> 5;
  const int row_e = tid >> 3;        // epilogue row 0..31
  const int c0    = (tid & 7) * 4;   // epilogue col quad 0..28
  const int r0 = rt*32, j0 = jt*32;

  const __hip_bfloat16* Wih = (const __hip_bfloat16*)(ws+OFF_WIH) + (size_t)d*G3*HD;
  const __hip_bfloat16* Whh = (const __hip_bfloat16*)(ws+OFF_WHH) + (size_t)d*G3*HD;
  const __hip_bfloat16* X16 = (const __hip_bfloat16*)(ws+OFF_X16);
  __hip_bfloat16* H16 = (__hip_bfloat16*)(ws+OFF_H16);        // [p][d][NB][HD]
  unsigned* flg = (unsigned*)(ws+OFF_FLG);
  float* part = (float*)(ws+OFF_PART);

  __shared__ float red[4][32][104];   // 53248B: K-slice partials (r|z|n at col offs 0/32/64)
  __shared__ float aux[256][25];      // 25600B, stride 25 (odd) -> conflict-free
                                      // [0:12) gi_rzn, [12:16) hst, [16:20) bhn, [20:24) wo

  const int kq = q*256 + lh*8;        // lane's base element offset in K

  bf16x8 Br[16], Bz[16];              // resident r,z weight fragments (128 VGPR)
  #define LOADRZ(W) { _Pragma("unroll") for (int ks=0;ks<16;++ks){ \
      Br[ks] = *(const bf16x8*)((W) + (size_t)(       j0 + lrow)*HD + kq + ks*16); \
      Bz[ks] = *(const bf16x8*)((W) + (size_t)(1024 + j0 + lrow)*HD + kq + ks*16); } }

  f32x16 acc0, acc1, acc2;
  f32x4 A4[4], Bn4[4];

  // gemm: 4 quarters; per quarter issue 4 Bn (cached) + 4 A (sc) loads, drain, 12 MFMA.
  auto gemm = [&](const __hip_bfloat16* pa, const __hip_bfloat16* pn){
    #pragma unroll
    for (int e=0;e<16;++e){ acc0[e]=0.f; acc1[e]=0.f; acc2[e]=0.f; }
    #pragma unroll
    for (int bt=0; bt<4; ++bt){
      #pragma unroll
      for (int ks=0;ks<4;++ks) Bn4[ks] = gload_nc(pn + (bt*4+ks)*16);
      #pragma unroll
      for (int ks=0;ks<4;++ks) A4[ks]  = gload_cc(pa + (bt*4+ks)*16);
      WAITV0;
      #pragma unroll
      for (int ks=0;ks<4;++ks){
        bf16x8 a  = __builtin_bit_cast(bf16x8, A4[ks]);
        bf16x8 bn = __builtin_bit_cast(bf16x8, Bn4[ks]);
        acc0 = __builtin_amdgcn_mfma_f32_32x32x16_bf16(a, Br[bt*4+ks], acc0,0,0,0);
        acc1 = __builtin_amdgcn_mfma_f32_32x32x16_bf16(a, Bz[bt*4+ks], acc1,0,0,0);
        acc2 = __builtin_amdgcn_mfma_f32_32x32x16_bf16(a, bn,          acc2,0,0,0);
      }
    }
  };

  #define WRED { _Pragma("unroll") for (int e=0;e<16;++e){ \
      int rl=(e&3)+8*(e>>2)+4*lh; \
      red[q][rl][     lrow]=acc0[e]; \
      red[q][rl][32 + lrow]=acc1[e]; \
      red[q][rl][64 + lrow]=acc2[e]; } }

  float v0[4], v1[4], v2[4];
  #define RRED { float4 s0={0,0,0,0}, s1={0,0,0,0}, s2={0,0,0,0}; \
    _Pragma("unroll") for (int qq=0;qq<4;++qq){ \
      float4 a_=*(const float4*)&red[qq][row_e][c0]; \
      float4 b_=*(const float4*)&red[qq][row_e][32+c0]; \
      float4 g_=*(const float4*)&red[qq][row_e][64+c0]; \
      s0.x+=a_.x; s0.y+=a_.y; s0.z+=a_.z; s0.w+=a_.w; \
      s1.x+=b_.x; s1.y+=b_.y; s1.z+=b_.z; s1.w+=b_.w; \
      s2.x+=g_.x; s2.y+=g_.y; s2.z+=g_.z; s2.w+=g_.w; } \
    v0[0]=s0.x; v0[1]=s0.y; v0[2]=s0.z; v0[3]=s0.w; \
    v1[0]=s1.x; v1[1]=s1.y; v1[2]=s1.z; v1[3]=s1.w; \
    v2[0]=s2.x; v2[1]=s2.y; v2[2]=s2.z; v2[3]=s2.w; }

  const __hip_bfloat16* pnW = Whh + (size_t)(2048 + j0 + lrow)*HD + kq;  // streamed gate-n rows

  // ---- INIT: gi = x @ W_ih^T (+ biases), stored to aux; hst=0 ----
  LOADRZ(Wih);
  gemm(X16 + (size_t)(r0 + lrow)*HD + kq, Wih + (size_t)(2048 + j0 + lrow)*HD + kq);
  WRED; __syncthreads(); RRED; __syncthreads();
  {
    const float* bih = d ? bihb : bihf;
    const float* bhh = d ? bhhb : bhhf;
    #pragma unroll
    for (int c=0;c<4;++c){
      const int col = j0 + c0 + c;
      aux[tid][0 +c] = v0[c] + bih[col]      + bhh[col];
      aux[tid][4 +c] = v1[c] + bih[1024+col] + bhh[1024+col];
      aux[tid][8 +c] = v2[c] + bih[2048+col];
      aux[tid][12+c] = 0.f;
      aux[tid][16+c] = bhh[2048+col];
      aux[tid][20+c] = wout[d*HD + col];
    }
  }
  LOADRZ(Whh);                        // resident recurrent r,z weights from here on

  const size_t hplane = (size_t)2*NB*HD;
  const __hip_bfloat16* paBase = H16 + (size_t)d*NB*HD + (size_t)(r0 + lrow)*HD + kq;
  const int grow = r0 + row_e;

  for (int t=0; t<NT; ++t){
    // wave-level spin on this wave's 8 producer flags (trivially passes at t=0)
    if (t){
      const unsigned tgt = (unsigned)t;
      unsigned* fp = flg + (size_t)(gg*32 + q*8 + (l & 7))*32;
      for(;;){
        unsigned v = (l < 8) ? __hip_atomic_load(fp, __ATOMIC_RELAXED, __HIP_MEMORY_SCOPE_AGENT) : tgt;
        if (__all((int)(v >= tgt))) break;
        __builtin_amdgcn_s_sleep(1);
      }
    }

    gemm(paBase + (size_t)(t&1)*hplane, pnW);
    WRED; __syncthreads(); RRED; __syncthreads();

    // epilogue: gates for 4 cols of one row; h-store (sc, 8B); out-partial
    {
      float pp = 0.f;
      unsigned hw[2];
      #pragma unroll
      for (int c2=0;c2<2;++c2){
        unsigned u = 0;
        #pragma unroll
        for (int c1=0;c1<2;++c1){
          const int c = c2*2 + c1;
          float rr = 1.f/(1.f+__expf(-(aux[tid][0+c] + v0[c])));
          float zz = 1.f/(1.f+__expf(-(aux[tid][4+c] + v1[c])));
          float ng = tanhf(aux[tid][8+c] + rr*(v2[c] + aux[tid][16+c]));
          float hn = (1.f-zz)*ng + zz*aux[tid][12+c];
          aux[tid][12+c] = hn;
          pp += hn * aux[tid][20+c];
          u |= ((unsigned)__builtin_bit_cast(unsigned short, (__bf16)hn)) << (16*c1);
        }
        hw[c2] = u;
      }
      __hip_bfloat16* hd = H16 + (size_t)((t+1)&1)*hplane + (size_t)d*NB*HD;
      u32x2 hv; hv[0]=hw[0]; hv[1]=hw[1];
      gstore_cc_d2(hd + (size_t)grow*HD + j0 + c0, hv);
      pp += __shfl_xor(pp, 1, 64);
      pp += __shfl_xor(pp, 2, 64);
      pp += __shfl_xor(pp, 4, 64);
      if ((l & 7) == 0) part[((size_t)grow*NT + t)*64 + d*32 + jt] = pp;
    }

    // release: per-wave drain, block-wide join, one flag bump per block
    WAITV0;
    __syncthreads();
    if (t+1 < NT && tid == 0) atomicAdd(flg + (size_t)(gg*32 + jt)*32, 1u);
  }
}

// ---------------- finalize: one wave per (b,t) output, f32 OUTPUT ----------------
__global__ __launch_bounds__(256) void finalize_kernel(
    const char* __restrict__ ws, const float* __restrict__ bout,
    float* __restrict__ out)
{
  int widx = blockIdx.x*4 + (threadIdx.x>>6);   // output index b*128+t, 32768 total
  int lane = threadIdx.x & 63;
  const float* part = (const float*)(ws+OFF_PART);
  float v = part[(size_t)widx*64 + lane];
  #pragma unroll
  for (int m=1;m<64;m<<=1) v += __shfl_xor(v, m, 64);
  if (lane==0) out[widx] = v + bout[0];
}

// ---------------- launch ----------------
extern "C" void kernel_launch(void* const* d_in, const int* in_sizes, int n_in,
                              void* d_out, int out_size, void* d_ws, size_t ws_size,
                              hipStream_t stream)
{
  const float* x    = (const float*)d_in[0];
  // d_in[1] = n (always 128 for this problem)
  const float* wihf = (const float*)d_in[2];
  const float* whhf = (const float*)d_in[3];
  const float* bihf = (const float*)d_in[4];
  const float* bhhf = (const float*)d_in[5];
  const float* wihb = (const float*)d_in[6];
  const float* whhb = (const float*)d_in[7];
  const float* bihb = (const float*)d_in[8];
  const float* bhhb = (const float*)d_in[9];
  const float* wout = (const float*)d_in[10];
  const float* bout = (const float*)d_in[11];
  char* ws = (char*)d_ws;
  float* out = (float*)d_out;

  prep_kernel<<<12288, 256, 0, stream>>>(x, wihf, whhf, wihb, whhb, ws);
  gru_persist<<<512, 256, 0, stream>>>(ws, bihf, bhhf, bihb, bhhb, wout);
  finalize_kernel<<<8192, 256, 0, stream>>>(ws, bout, out);
}

// Round 16
// 1059.048 us; speedup vs baseline: 2.4047x; 1.3854x over previous
//
#include <hip/hip_runtime.h>
#include <hip/hip_bf16.h>

typedef __attribute__((ext_vector_type(8))) __bf16 bf16x8;
typedef __attribute__((ext_vector_type(16))) float f32x16;
typedef __attribute__((ext_vector_type(4)))  float f32x4;

#define NB 256     // batch
#define HD 1024    // hidden
#define G3 3072    // 3*H
#define NT 128     // time steps

// ---------------- workspace layout (bytes) ----------------
static const size_t OFF_WHH  = 0;                                   // [d][3072][1024] bf16 (natural)
static const size_t OFF_WIH  = OFF_WHH + (size_t)2*G3*HD*2;         // [d][3072][1024] bf16 (natural)
static const size_t OFF_X16  = OFF_WIH + (size_t)2*G3*HD*2;         // [256][1024] bf16 (natural)
static const size_t OFF_FLG  = OFF_X16 + (size_t)NB*HD*2;           // 8 groups x 32 producers, 128B stride = 64KB
static const size_t OFF_H16  = OFF_FLG + 65536;                     // [p][d][256][1024] bf16 (natural)
static const size_t OFF_PART = OFF_H16 + (size_t)4*NB*HD*2;         // [b][t][64] f32
// total ~36.2 MB

// ---------------- prep: cast to bf16, zero h16 plane 0, zero flags ----------------
__global__ __launch_bounds__(256) void prep_kernel(
    const float* __restrict__ x,    const float* __restrict__ wihf,
    const float* __restrict__ whhf, const float* __restrict__ wihb,
    const float* __restrict__ whhb, char* __restrict__ ws)
{
  size_t i = (size_t)blockIdx.x*256 + threadIdx.x;   // grid covers 3145728
  __hip_bfloat16* whh = (__hip_bfloat16*)(ws+OFF_WHH);
  __hip_bfloat16* wih = (__hip_bfloat16*)(ws+OFF_WIH);
  __hip_bfloat16* x16 = (__hip_bfloat16*)(ws+OFF_X16);
  __hip_bfloat16* h16 = (__hip_bfloat16*)(ws+OFF_H16);
  if (i < 16384) ((unsigned*)(ws+OFF_FLG))[i] = 0u;
  if (i < (size_t)G3*HD) {
    whh[i]                 = __float2bfloat16(whhf[i]);
    whh[(size_t)G3*HD + i] = __float2bfloat16(whhb[i]);
    wih[i]                 = __float2bfloat16(wihf[i]);
    wih[(size_t)G3*HD + i] = __float2bfloat16(wihb[i]);
  }
  if (i < (size_t)NB*HD)   x16[i] = __float2bfloat16(x[i]);
  if (i < (size_t)2*NB*HD) h16[i]  = __float2bfloat16(0.f);   // plane 0, both dirs
}

// ---------------- coherent-bypass (sc0 sc1) load/store helpers ----------------
__device__ inline f32x4 gload_cc(const void* p){
  f32x4 r;
  asm volatile("global_load_dwordx4 %0, %1, off sc0 sc1" : "=v"(r) : "v"(p) : "memory");
  return r;
}
__device__ inline void gstore_cc(void* p, f32x4 v){
  asm volatile("global_store_dwordx4 %0, %1, off sc0 sc1" :: "v"(p), "v"(v) : "memory");
}

// ---------------- persistent bidirectional GRU ----------------
// EXACT round-9 skeleton (proven: 236 VGPR, no spill, 116MB FETCH) with two
// proven grafts: (1) per-producer flag sync (r13/r14) replacing the monolithic
// 32-block barrier; (2) fast tanh. 256 blocks (1/CU via 102KB LDS), 256 thr =
// 4 waves (K-slices of 256). g8 = bid&7 = (d<<2)|rt; jt = bid>>3.
// W fragments resident in VGPR (B[3][16]); h exchange sc0sc1 (L3, XCD-safe).
__global__ __launch_bounds__(256,1)
void gru_persist(char* __restrict__ ws,
                 const float* __restrict__ bihf, const float* __restrict__ bhhf,
                 const float* __restrict__ bihb, const float* __restrict__ bhhb,
                 const float* __restrict__ wout)
{
  const int bid = blockIdx.x;
  const int g8  = bid & 7;           // sync group
  const int d   = g8 >> 2;           // direction
  const int rt  = g8 & 3;            // row tile (64 rows)
  const int jt  = bid >> 3;          // hcol tile (32 cols)
  const int tid = threadIdx.x;
  const int q   = tid >> 6;          // K-slice 0..3 (256 each)
  const int l   = tid & 63;
  const int lrow = l & 31;           // fragment row/col lane component
  const int lh   = l >> 5;           // lane half
  const int erow = l & 15;           // epilogue row within wave's quarter
  const int ec   = l >> 4;           // epilogue col chunk 0..3
  const int r0 = rt*64, j0 = jt*32;

  const __hip_bfloat16* Wih = (const __hip_bfloat16*)(ws+OFF_WIH) + (size_t)d*G3*HD;
  const __hip_bfloat16* Whh = (const __hip_bfloat16*)(ws+OFF_WHH) + (size_t)d*G3*HD;
  const __hip_bfloat16* X16 = (const __hip_bfloat16*)(ws+OFF_X16);
  __hip_bfloat16* H16 = (__hip_bfloat16*)(ws+OFF_H16);        // [p][d][NB][HD]
  unsigned* flg = (unsigned*)(ws+OFF_FLG);
  float* part = (float*)(ws+OFF_PART);

  __shared__ float red[4][64][100];   // K-slice partials, padded (102.4 KB)

  // per-lane element offset of the wave's K-slice chunks: chunk = q*32 + 2*ks + lh
  const int kbase = (q*32 + lh)*8;

  bf16x8 B[3][16];                    // resident weight fragments
  auto loadB = [&](const __hip_bfloat16* Wsrc){
    #pragma unroll
    for (int g=0; g<3; ++g){
      const __hip_bfloat16* p0 = Wsrc + (size_t)(g*1024 + j0 + lrow)*HD + kbase;
      #pragma unroll
      for (int ks=0; ks<16; ++ks) B[g][ks] = *(const bf16x8*)(p0 + ks*16);
    }
  };

  f32x16 acc[2][3];
  // GEMM with coherent-bypass A loads, double-buffered by bt-parity,
  // counted vmcnt(8) (sched_barrier(0) after each wait per rule #18).
  auto gemm_cc = [&](const __hip_bfloat16* Asrc){
    #pragma unroll
    for (int mi=0;mi<2;++mi)
      #pragma unroll
      for (int g=0;g<3;++g)
        #pragma unroll
        for (int e=0;e<16;++e) acc[mi][g][e] = 0.f;
    const __hip_bfloat16* pa0 = Asrc + (size_t)(r0 + lrow)*HD + kbase;
    const __hip_bfloat16* pa1 = pa0 + 32*HD;
    f32x4 A0a[4], A0b[4], A1a[4], A1b[4];   // two named buffers (static idx, rule #20)
    #pragma unroll
    for (int ks=0; ks<4; ++ks){ A0a[ks]=gload_cc(pa0+ks*16);      A1a[ks]=gload_cc(pa1+ks*16); }
    #pragma unroll
    for (int ks=0; ks<4; ++ks){ A0b[ks]=gload_cc(pa0+(4+ks)*16);  A1b[ks]=gload_cc(pa1+(4+ks)*16); }

    // bt=0: consume a-buffers, refill with bt=2
    asm volatile("s_waitcnt vmcnt(8)" ::: "memory");
    __builtin_amdgcn_sched_barrier(0);
    #pragma unroll
    for (int ks=0; ks<4; ++ks){
      bf16x8 a0 = __builtin_bit_cast(bf16x8, A0a[ks]);
      bf16x8 a1 = __builtin_bit_cast(bf16x8, A1a[ks]);
      #pragma unroll
      for (int g=0; g<3; ++g){
        acc[0][g] = __builtin_amdgcn_mfma_f32_32x32x16_bf16(a0, B[g][ks], acc[0][g],0,0,0);
        acc[1][g] = __builtin_amdgcn_mfma_f32_32x32x16_bf16(a1, B[g][ks], acc[1][g],0,0,0);
      }
    }
    #pragma unroll
    for (int ks=0; ks<4; ++ks){ A0a[ks]=gload_cc(pa0+(8+ks)*16);  A1a[ks]=gload_cc(pa1+(8+ks)*16); }

    // bt=1: consume b-buffers, refill with bt=3
    asm volatile("s_waitcnt vmcnt(8)" ::: "memory");
    __builtin_amdgcn_sched_barrier(0);
    #pragma unroll
    for (int ks=0; ks<4; ++ks){
      bf16x8 a0 = __builtin_bit_cast(bf16x8, A0b[ks]);
      bf16x8 a1 = __builtin_bit_cast(bf16x8, A1b[ks]);
      #pragma unroll
      for (int g=0; g<3; ++g){
        acc[0][g] = __builtin_amdgcn_mfma_f32_32x32x16_bf16(a0, B[g][4+ks], acc[0][g],0,0,0);
        acc[1][g] = __builtin_amdgcn_mfma_f32_32x32x16_bf16(a1, B[g][4+ks], acc[1][g],0,0,0);
      }
    }
    #pragma unroll
    for (int ks=0; ks<4; ++ks){ A0b[ks]=gload_cc(pa0+(12+ks)*16); A1b[ks]=gload_cc(pa1+(12+ks)*16); }

    // bt=2: consume a-buffers
    asm volatile("s_waitcnt vmcnt(8)" ::: "memory");
    __builtin_amdgcn_sched_barrier(0);
    #pragma unroll
    for (int ks=0; ks<4; ++ks){
      bf16x8 a0 = __builtin_bit_cast(bf16x8, A0a[ks]);
      bf16x8 a1 = __builtin_bit_cast(bf16x8, A1a[ks]);
      #pragma unroll
      for (int g=0; g<3; ++g){
        acc[0][g] = __builtin_amdgcn_mfma_f32_32x32x16_bf16(a0, B[g][8+ks], acc[0][g],0,0,0);
        acc[1][g] = __builtin_amdgcn_mfma_f32_32x32x16_bf16(a1, B[g][8+ks], acc[1][g],0,0,0);
      }
    }

    // bt=3: consume b-buffers
    asm volatile("s_waitcnt vmcnt(0)" ::: "memory");
    __builtin_amdgcn_sched_barrier(0);
    #pragma unroll
    for (int ks=0; ks<4; ++ks){
      bf16x8 a0 = __builtin_bit_cast(bf16x8, A0b[ks]);
      bf16x8 a1 = __builtin_bit_cast(bf16x8, A1b[ks]);
      #pragma unroll
      for (int g=0; g<3; ++g){
        acc[0][g] = __builtin_amdgcn_mfma_f32_32x32x16_bf16(a0, B[g][12+ks], acc[0][g],0,0,0);
        acc[1][g] = __builtin_amdgcn_mfma_f32_32x32x16_bf16(a1, B[g][12+ks], acc[1][g],0,0,0);
      }
    }
  };

  float val[3][8];
  auto reduce = [&](){
    #pragma unroll
    for (int mi=0;mi<2;++mi)
      #pragma unroll
      for (int g=0;g<3;++g)
        #pragma unroll
        for (int e=0;e<16;++e){
          int rl = mi*32 + (e&3) + 8*(e>>2) + 4*lh;   // validated C/D row map
          red[q][rl][g*32 + lrow] = acc[mi][g][e];
        }
    __syncthreads();
    #pragma unroll
    for (int g=0; g<3; ++g){
      #pragma unroll
      for (int c=0;c<8;++c) val[g][c] = 0.f;
      #pragma unroll
      for (int qq=0; qq<4; ++qq){
        const float* base = &red[qq][q*16+erow][g*32 + ec*8];
        float4 v0 = *(const float4*)base;
        float4 v1 = *(const float4*)(base+4);
        val[g][0]+=v0.x; val[g][1]+=v0.y; val[g][2]+=v0.z; val[g][3]+=v0.w;
        val[g][4]+=v1.x; val[g][5]+=v1.y; val[g][6]+=v1.z; val[g][7]+=v1.w;
      }
    }
    __syncthreads();
  };

  // ---- step -1: gi = x @ W_ih^T (+ biases folded), kept in registers ----
  loadB(Wih);
  gemm_cc(X16);
  reduce();
  const float* bih = d ? bihb : bihf;
  const float* bhh = d ? bhhb : bhhf;
  const int cg = j0 + ec*8;           // lane's 8-col chunk within gate
  float gir[8], giz[8], gin[8], bhn[8], wo8[8], h[8];
  #pragma unroll
  for (int c=0;c<8;++c){
    gir[c] = val[0][c] + bih[cg+c]      + bhh[cg+c];
    giz[c] = val[1][c] + bih[1024+cg+c] + bhh[1024+cg+c];
    gin[c] = val[2][c] + bih[2048+cg+c];
    bhn[c] = bhh[2048+cg+c];
    wo8[c] = wout[d*HD + cg + c];
    h[c]   = 0.f;
  }

  loadB(Whh);                          // recurrent weights resident from here on
  const int myrow = r0 + q*16 + erow;  // global batch row this lane owns
  const size_t hplane = (size_t)2*NB*HD;

  for (int t=0; t<NT; ++t){
    // per-wave spin: wave q waits only on its 8 producers (jt = 8q..8q+7)
    if (t){
      const unsigned tgt = (unsigned)t;
      unsigned* fp = flg + (size_t)(g8*32 + q*8 + (l & 7))*32;
      for(;;){
        unsigned v = (l < 8) ? __hip_atomic_load(fp, __ATOMIC_RELAXED, __HIP_MEMORY_SCOPE_AGENT) : tgt;
        if (__all((int)(v >= tgt))) break;
        __builtin_amdgcn_s_sleep(1);
      }
    }

    const __hip_bfloat16* hs = H16 + (size_t)(t&1)*hplane + (size_t)d*NB*HD;
    gemm_cc(hs);
    reduce();
    bf16x8 hv;
    float pp = 0.f;
    #pragma unroll
    for (int c=0;c<8;++c){
      float rr = 1.f/(1.f+__expf(-(gir[c]+val[0][c])));
      float zz = 1.f/(1.f+__expf(-(giz[c]+val[1][c])));
      float ar = gin[c] + rr*(val[2][c]+bhn[c]);
      float ng = 1.f - 2.f/(1.f + __expf(2.f*ar));   // fast tanh, saturates to +-1
      h[c] = (1.f-zz)*ng + zz*h[c];
      hv[c] = (__bf16)h[c];
      pp += h[c]*wo8[c];
    }
    __hip_bfloat16* hd = H16 + (size_t)((t+1)&1)*hplane + (size_t)d*NB*HD;
    gstore_cc(hd + (size_t)myrow*HD + cg, __builtin_bit_cast(f32x4, hv));
    pp += __shfl_xor(pp, 16, 64);
    pp += __shfl_xor(pp, 32, 64);
    if (l < 16) part[((size_t)myrow*NT + t)*64 + d*32 + jt] = pp;

    // release: per-wave drain of own h stores (vmcnt is per-wave), block join
    // (protects red + orders all waves' stores before the flag), one bump.
    asm volatile("s_waitcnt vmcnt(0)" ::: "memory");
    __syncthreads();
    if (t+1 < NT && tid == 0) atomicAdd(flg + (size_t)(g8*32 + jt)*32, 1u);
  }
}

// ---------------- finalize: one wave per (b,t) output, f32 OUTPUT ----------------
__global__ __launch_bounds__(256) void finalize_kernel(
    const char* __restrict__ ws, const float* __restrict__ bout,
    float* __restrict__ out)
{
  int widx = blockIdx.x*4 + (threadIdx.x>>6);   // output index b*128+t, 32768 total
  int lane = threadIdx.x & 63;
  const float* part = (const float*)(ws+OFF_PART);
  float v = part[(size_t)widx*64 + lane];
  #pragma unroll
  for (int m=1;m<64;m<<=1) v += __shfl_xor(v, m, 64);
  if (lane==0) out[widx] = v + bout[0];
}

// ---------------- launch ----------------
extern "C" void kernel_launch(void* const* d_in, const int* in_sizes, int n_in,
                              void* d_out, int out_size, void* d_ws, size_t ws_size,
                              hipStream_t stream)
{
  const float* x    = (const float*)d_in[0];
  // d_in[1] = n (always 128 for this problem)
  const float* wihf = (const float*)d_in[2];
  const float* whhf = (const float*)d_in[3];
  const float* bihf = (const float*)d_in[4];
  const float* bhhf = (const float*)d_in[5];
  const float* wihb = (const float*)d_in[6];
  const float* whhb = (const float*)d_in[7];
  const float* bihb = (const float*)d_in[8];
  const float* bhhb = (const float*)d_in[9];
  const float* wout = (const float*)d_in[10];
  const float* bout = (const float*)d_in[11];
  char* ws = (char*)d_ws;
  float* out = (float*)d_out;

  prep_kernel<<<12288, 256, 0, stream>>>(x, wihf, whhf, wihb, whhb, ws);
  gru_persist<<<256, 256, 0, stream>>>(ws, bihf, bhhf, bihb, bhhb, wout);
  finalize_kernel<<<8192, 256, 0, stream>>>(ws, bout, out);
}

// Round 17
// 1016.910 us; speedup vs baseline: 2.5044x; 1.0414x over previous
//
#include <hip/hip_runtime.h>
#include <hip/hip_bf16.h>

typedef __attribute__((ext_vector_type(8))) __bf16 bf16x8;
typedef __attribute__((ext_vector_type(16))) float f32x16;
typedef __attribute__((ext_vector_type(4)))  float f32x4;

#define NB 256     // batch
#define HD 1024    // hidden
#define G3 3072    // 3*H
#define NT 128     // time steps

// ---------------- workspace layout (bytes) ----------------
static const size_t OFF_WHH  = 0;                                   // [d][3072][1024] bf16 (natural)
static const size_t OFF_WIH  = OFF_WHH + (size_t)2*G3*HD*2;         // [d][3072][1024] bf16 (natural)
static const size_t OFF_X16  = OFF_WIH + (size_t)2*G3*HD*2;         // [256][1024] bf16 (natural)
static const size_t OFF_FLG  = OFF_X16 + (size_t)NB*HD*2;           // flags (32KB) + xtab/xcnt, 64KB total
static const size_t OFF_XTAB = OFF_FLG + 32768;                     // 256 u32: per-block XCC id
static const size_t OFF_XCNT = OFF_XTAB + 1024;                     // 1 u32 arrival counter
static const size_t OFF_H16  = OFF_FLG + 65536;                     // [p][d][256][1024] bf16 (natural)
static const size_t OFF_PART = OFF_H16 + (size_t)4*NB*HD*2;         // [b][t][64] f32
// total ~36.2 MB

// ---------------- prep: cast to bf16, zero h16 plane 0, zero flags ----------------
__global__ __launch_bounds__(256) void prep_kernel(
    const float* __restrict__ x,    const float* __restrict__ wihf,
    const float* __restrict__ whhf, const float* __restrict__ wihb,
    const float* __restrict__ whhb, char* __restrict__ ws)
{
  size_t i = (size_t)blockIdx.x*256 + threadIdx.x;   // grid covers 3145728
  __hip_bfloat16* whh = (__hip_bfloat16*)(ws+OFF_WHH);
  __hip_bfloat16* wih = (__hip_bfloat16*)(ws+OFF_WIH);
  __hip_bfloat16* x16 = (__hip_bfloat16*)(ws+OFF_X16);
  __hip_bfloat16* h16 = (__hip_bfloat16*)(ws+OFF_H16);
  if (i < 16384) ((unsigned*)(ws+OFF_FLG))[i] = 0u;   // zeros flags + xtab + xcnt each launch
  if (i < (size_t)G3*HD) {
    whh[i]                 = __float2bfloat16(whhf[i]);
    whh[(size_t)G3*HD + i] = __float2bfloat16(whhb[i]);
    wih[i]                 = __float2bfloat16(wihf[i]);
    wih[(size_t)G3*HD + i] = __float2bfloat16(wihb[i]);
  }
  if (i < (size_t)NB*HD)   x16[i] = __float2bfloat16(x[i]);
  if (i < (size_t)2*NB*HD) h16[i]  = __float2bfloat16(0.f);   // plane 0, both dirs
}

// ---------------- load/store helpers ----------------
// slow path: sc0 sc1 = coherence-point (L3) access, correct on any placement.
__device__ inline f32x4 gload_cc(const void* p){
  f32x4 r;
  asm volatile("global_load_dwordx4 %0, %1, off sc0 sc1" : "=v"(r) : "v"(p) : "memory");
  return r;
}
__device__ inline void gstore_cc(void* p, f32x4 v){
  asm volatile("global_store_dwordx4 %0, %1, off sc0 sc1" :: "v"(p), "v"(v) : "memory");
}
// fast path (co-XCD group only): plain store (write-through to the shared L2),
// sc0 load (bypass possibly-stale L1, read the shared L2 directly).
__device__ inline f32x4 gload_l2(const void* p){
  f32x4 r;
  asm volatile("global_load_dwordx4 %0, %1, off sc0" : "=v"(r) : "v"(p) : "memory");
  return r;
}
__device__ inline void gstore_l2(void* p, f32x4 v){
  asm volatile("global_store_dwordx4 %0, %1, off" :: "v"(p), "v"(v) : "memory");
}
__device__ inline unsigned gload_u32_cc(const void* p){
  unsigned r;
  asm volatile("global_load_dword %0, %1, off sc0 sc1" : "=v"(r) : "v"(p) : "memory");
  return r;
}
__device__ inline void gstore_u32_cc(void* p, unsigned v){
  asm volatile("global_store_dword %0, %1, off sc0 sc1" :: "v"(p), "v"(v) : "memory");
}

// GEMM body, parameterized on the A-operand loader (LOADH).
#define GEMM_BODY(ASRC, LOADH) { \
    _Pragma("unroll") for (int mi=0;mi<2;++mi) \
      _Pragma("unroll") for (int g=0;g<3;++g) \
        _Pragma("unroll") for (int e=0;e<16;++e) acc[mi][g][e] = 0.f; \
    const __hip_bfloat16* pa0 = (ASRC) + (size_t)(r0 + lrow)*HD + kbase; \
    const __hip_bfloat16* pa1 = pa0 + 32*HD; \
    f32x4 A0a[4], A0b[4], A1a[4], A1b[4]; \
    _Pragma("unroll") for (int ks=0; ks<4; ++ks){ A0a[ks]=LOADH(pa0+ks*16);      A1a[ks]=LOADH(pa1+ks*16); } \
    _Pragma("unroll") for (int ks=0; ks<4; ++ks){ A0b[ks]=LOADH(pa0+(4+ks)*16);  A1b[ks]=LOADH(pa1+(4+ks)*16); } \
    asm volatile("s_waitcnt vmcnt(8)" ::: "memory"); \
    __builtin_amdgcn_sched_barrier(0); \
    _Pragma("unroll") for (int ks=0; ks<4; ++ks){ \
      bf16x8 a0 = __builtin_bit_cast(bf16x8, A0a[ks]); \
      bf16x8 a1 = __builtin_bit_cast(bf16x8, A1a[ks]); \
      _Pragma("unroll") for (int g=0; g<3; ++g){ \
        acc[0][g] = __builtin_amdgcn_mfma_f32_32x32x16_bf16(a0, B[g][ks], acc[0][g],0,0,0); \
        acc[1][g] = __builtin_amdgcn_mfma_f32_32x32x16_bf16(a1, B[g][ks], acc[1][g],0,0,0); \
      } \
    } \
    _Pragma("unroll") for (int ks=0; ks<4; ++ks){ A0a[ks]=LOADH(pa0+(8+ks)*16);  A1a[ks]=LOADH(pa1+(8+ks)*16); } \
    asm volatile("s_waitcnt vmcnt(8)" ::: "memory"); \
    __builtin_amdgcn_sched_barrier(0); \
    _Pragma("unroll") for (int ks=0; ks<4; ++ks){ \
      bf16x8 a0 = __builtin_bit_cast(bf16x8, A0b[ks]); \
      bf16x8 a1 = __builtin_bit_cast(bf16x8, A1b[ks]); \
      _Pragma("unroll") for (int g=0; g<3; ++g){ \
        acc[0][g] = __builtin_amdgcn_mfma_f32_32x32x16_bf16(a0, B[g][4+ks], acc[0][g],0,0,0); \
        acc[1][g] = __builtin_amdgcn_mfma_f32_32x32x16_bf16(a1, B[g][4+ks], acc[1][g],0,0,0); \
      } \
    } \
    _Pragma("unroll") for (int ks=0; ks<4; ++ks){ A0b[ks]=LOADH(pa0+(12+ks)*16); A1b[ks]=LOADH(pa1+(12+ks)*16); } \
    asm volatile("s_waitcnt vmcnt(8)" ::: "memory"); \
    __builtin_amdgcn_sched_barrier(0); \
    _Pragma("unroll") for (int ks=0; ks<4; ++ks){ \
      bf16x8 a0 = __builtin_bit_cast(bf16x8, A0a[ks]); \
      bf16x8 a1 = __builtin_bit_cast(bf16x8, A1a[ks]); \
      _Pragma("unroll") for (int g=0; g<3; ++g){ \
        acc[0][g] = __builtin_amdgcn_mfma_f32_32x32x16_bf16(a0, B[g][8+ks], acc[0][g],0,0,0); \
        acc[1][g] = __builtin_amdgcn_mfma_f32_32x32x16_bf16(a1, B[g][8+ks], acc[1][g],0,0,0); \
      } \
    } \
    asm volatile("s_waitcnt vmcnt(0)" ::: "memory"); \
    __builtin_amdgcn_sched_barrier(0); \
    _Pragma("unroll") for (int ks=0; ks<4; ++ks){ \
      bf16x8 a0 = __builtin_bit_cast(bf16x8, A0b[ks]); \
      bf16x8 a1 = __builtin_bit_cast(bf16x8, A1b[ks]); \
      _Pragma("unroll") for (int g=0; g<3; ++g){ \
        acc[0][g] = __builtin_amdgcn_mfma_f32_32x32x16_bf16(a0, B[g][12+ks], acc[0][g],0,0,0); \
        acc[1][g] = __builtin_amdgcn_mfma_f32_32x32x16_bf16(a1, B[g][12+ks], acc[1][g],0,0,0); \
      } \
    } \
  }

// ---------------- persistent bidirectional GRU ----------------
// Round-16 skeleton (proven 1059us) + co-XCD L2 h-exchange with runtime
// verification. g8 = bid&7 = (d<<2)|rt; under bid%8 XCD round-robin all 32
// blocks of a group share one XCD/L2 -> plain-store + sc0-load h exchange
// (no L3 round trips, 32x panel redundancy absorbed by L2). Verified at
// runtime via HW_REG_XCC_ID [m09]; non-co-XCD groups fall back to sc0sc1.
__global__ __launch_bounds__(256,1)
void gru_persist(char* __restrict__ ws,
                 const float* __restrict__ bihf, const float* __restrict__ bhhf,
                 const float* __restrict__ bihb, const float* __restrict__ bhhb,
                 const float* __restrict__ wout)
{
  const int bid = blockIdx.x;
  const int g8  = bid & 7;           // sync group
  const int d   = g8 >> 2;           // direction
  const int rt  = g8 & 3;            // row tile (64 rows)
  const int jt  = bid >> 3;          // hcol tile (32 cols)
  const int tid = threadIdx.x;
  const int q   = tid >> 6;          // K-slice 0..3 (256 each)
  const int l   = tid & 63;
  const int lrow = l & 31;
  const int lh   = l >> 5;
  const int erow = l & 15;
  const int ec   = l >> 4;
  const int r0 = rt*64, j0 = jt*32;

  const __hip_bfloat16* Wih = (const __hip_bfloat16*)(ws+OFF_WIH) + (size_t)d*G3*HD;
  const __hip_bfloat16* Whh = (const __hip_bfloat16*)(ws+OFF_WHH) + (size_t)d*G3*HD;
  const __hip_bfloat16* X16 = (const __hip_bfloat16*)(ws+OFF_X16);
  __hip_bfloat16* H16 = (__hip_bfloat16*)(ws+OFF_H16);        // [p][d][NB][HD]
  unsigned* flg  = (unsigned*)(ws+OFF_FLG);
  unsigned* xtab = (unsigned*)(ws+OFF_XTAB);
  unsigned* xcnt = (unsigned*)(ws+OFF_XCNT);
  float* part = (float*)(ws+OFF_PART);

  __shared__ float red[4][64][100];   // K-slice partials, padded (102.4 KB)
  __shared__ unsigned oksh;

  const int kbase = (q*32 + lh)*8;

  bf16x8 B[3][16];                    // resident weight fragments
  auto loadB = [&](const __hip_bfloat16* Wsrc){
    #pragma unroll
    for (int g=0; g<3; ++g){
      const __hip_bfloat16* p0 = Wsrc + (size_t)(g*1024 + j0 + lrow)*HD + kbase;
      #pragma unroll
      for (int ks=0; ks<16; ++ks) B[g][ks] = *(const bf16x8*)(p0 + ks*16);
    }
  };

  f32x16 acc[2][3];
  float val[3][8];
  auto reduce = [&](){
    #pragma unroll
    for (int mi=0;mi<2;++mi)
      #pragma unroll
      for (int g=0;g<3;++g)
        #pragma unroll
        for (int e=0;e<16;++e){
          int rl = mi*32 + (e&3) + 8*(e>>2) + 4*lh;   // validated C/D row map
          red[q][rl][g*32 + lrow] = acc[mi][g][e];
        }
    __syncthreads();
    #pragma unroll
    for (int g=0; g<3; ++g){
      #pragma unroll
      for (int c=0;c<8;++c) val[g][c] = 0.f;
      #pragma unroll
      for (int qq=0; qq<4; ++qq){
        const float* base = &red[qq][q*16+erow][g*32 + ec*8];
        float4 v0 = *(const float4*)base;
        float4 v1 = *(const float4*)(base+4);
        val[g][0]+=v0.x; val[g][1]+=v0.y; val[g][2]+=v0.z; val[g][3]+=v0.w;
        val[g][4]+=v1.x; val[g][5]+=v1.y; val[g][6]+=v1.z; val[g][7]+=v1.w;
      }
    }
    __syncthreads();
  };

  // ---- publish own XCC id (one-time, overlaps INIT) ----
  unsigned xcc;
  asm volatile("s_getreg_b32 %0, hwreg(HW_REG_XCC_ID)" : "=s"(xcc));
  if (tid == 0){
    gstore_u32_cc(xtab + bid, xcc);
    asm volatile("s_waitcnt vmcnt(0)" ::: "memory");
    atomicAdd(xcnt, 1u);
  }

  // ---- step -1: gi = x @ W_ih^T (+ biases folded), kept in registers ----
  loadB(Wih);
  GEMM_BODY(X16, gload_l2);           // X16 is read-only this kernel: cached-safe
  reduce();
  const float* bih = d ? bihb : bihf;
  const float* bhh = d ? bhhb : bhhf;
  const int cg = j0 + ec*8;
  float gir[8], giz[8], gin[8], bhn[8], wo8[8], h[8];
  #pragma unroll
  for (int c=0;c<8;++c){
    gir[c] = val[0][c] + bih[cg+c]      + bhh[cg+c];
    giz[c] = val[1][c] + bih[1024+cg+c] + bhh[1024+cg+c];
    gin[c] = val[2][c] + bih[2048+cg+c];
    bhn[c] = bhh[2048+cg+c];
    wo8[c] = wout[d*HD + cg + c];
    h[c]   = 0.f;
  }
  loadB(Whh);                          // recurrent weights resident from here on

  // ---- one-time co-XCD group check (all 256 blocks resident: 1/CU by LDS) ----
  if (tid == 0){
    while (__hip_atomic_load(xcnt, __ATOMIC_RELAXED, __HIP_MEMORY_SCOPE_AGENT) < 256u)
      __builtin_amdgcn_s_sleep(2);
    unsigned all_ok = 1u, ref = gload_u32_cc(xtab + g8);
    asm volatile("s_waitcnt vmcnt(0)" ::: "memory");
    for (int i=1; i<32; ++i){
      unsigned v = gload_u32_cc(xtab + g8 + i*8);
      asm volatile("s_waitcnt vmcnt(0)" ::: "memory");
      if (v != ref) all_ok = 0u;
    }
    oksh = all_ok;
  }
  __syncthreads();
  const bool okf = (oksh != 0u);       // group-uniform

  const int myrow = r0 + q*16 + erow;
  const size_t hplane = (size_t)2*NB*HD;

  for (int t=0; t<NT; ++t){
    // per-wave spin: wave q waits only on its 8 producers (jt = 8q..8q+7)
    if (t){
      const unsigned tgt = (unsigned)t;
      unsigned* fp = flg + (size_t)(g8*32 + q*8 + (l & 7))*32;
      for(;;){
        unsigned v = (l < 8) ? __hip_atomic_load(fp, __ATOMIC_RELAXED, __HIP_MEMORY_SCOPE_AGENT) : tgt;
        if (__all((int)(v >= tgt))) break;
        __builtin_amdgcn_s_sleep(1);
      }
    }

    const __hip_bfloat16* hs = H16 + (size_t)(t&1)*hplane + (size_t)d*NB*HD;
    if (okf) { GEMM_BODY(hs, gload_l2); } else { GEMM_BODY(hs, gload_cc); }
    reduce();

    bf16x8 hv;
    float pp = 0.f;
    #pragma unroll
    for (int c=0;c<8;++c){
      float rr = 1.f/(1.f+__expf(-(gir[c]+val[0][c])));
      float zz = 1.f/(1.f+__expf(-(giz[c]+val[1][c])));
      float ar = gin[c] + rr*(val[2][c]+bhn[c]);
      float ng = 1.f - 2.f/(1.f + __expf(2.f*ar));   // fast tanh
      h[c] = (1.f-zz)*ng + zz*h[c];
      hv[c] = (__bf16)h[c];
      pp += h[c]*wo8[c];
    }
    __hip_bfloat16* hd = H16 + (size_t)((t+1)&1)*hplane + (size_t)d*NB*HD;
    f32x4 hvv = __builtin_bit_cast(f32x4, hv);
    if (okf) gstore_l2(hd + (size_t)myrow*HD + cg, hvv);
    else     gstore_cc(hd + (size_t)myrow*HD + cg, hvv);
    pp += __shfl_xor(pp, 16, 64);
    pp += __shfl_xor(pp, 32, 64);
    if (l < 16) part[((size_t)myrow*NT + t)*64 + d*32 + jt] = pp;

    // release: per-wave drain of own h stores, block join, one flag bump
    asm volatile("s_waitcnt vmcnt(0)" ::: "memory");
    __syncthreads();
    if (t+1 < NT && tid == 0) atomicAdd(flg + (size_t)(g8*32 + jt)*32, 1u);
  }
}

// ---------------- finalize: one wave per (b,t) output, f32 OUTPUT ----------------
__global__ __launch_bounds__(256) void finalize_kernel(
    const char* __restrict__ ws, const float* __restrict__ bout,
    float* __restrict__ out)
{
  int widx = blockIdx.x*4 + (threadIdx.x>>6);   // output index b*128+t, 32768 total
  int lane = threadIdx.x & 63;
  const float* part = (const float*)(ws+OFF_PART);
  float v = part[(size_t)widx*64 + lane];
  #pragma unroll
  for (int m=1;m<64;m<<=1) v += __shfl_xor(v, m, 64);
  if (lane==0) out[widx] = v + bout[0];
}

// ---------------- launch ----------------
extern "C" void kernel_launch(void* const* d_in, const int* in_sizes, int n_in,
                              void* d_out, int out_size, void* d_ws, size_t ws_size,
                              hipStream_t stream)
{
  const float* x    = (const float*)d_in[0];
  // d_in[1] = n (always 128 for this problem)
  const float* wihf = (const float*)d_in[2];
  const float* whhf = (const float*)d_in[3];
  const float* bihf = (const float*)d_in[4];
  const float* bhhf = (const float*)d_in[5];
  const float* wihb = (const float*)d_in[6];
  const float* whhb = (const float*)d_in[7];
  const float* bihb = (const float*)d_in[8];
  const float* bhhb = (const float*)d_in[9];
  const float* wout = (const float*)d_in[10];
  const float* bout = (const float*)d_in[11];
  char* ws = (char*)d_ws;
  float* out = (float*)d_out;

  prep_kernel<<<12288, 256, 0, stream>>>(x, wihf, whhf, wihb, whhb, ws);
  gru_persist<<<256, 256, 0, stream>>>(ws, bihf, bhhf, bihb, bhhb, wout);
  finalize_kernel<<<8192, 256, 0, stream>>>(ws, bout, out);
}